// Round 7
// baseline (43286.435 us; speedup 1.0000x reference)
//
#include <hip/hip_runtime.h>

#define DEV __device__ __forceinline__

constexpr int Bb = 64, Tt = 512, Ii = 256, Hd = 512;
constexpr int NWG = 256, NTHR = 512;          // 2 engines × 256 threads
constexpr int BbHd = Bb * Hd, BbIi = Bb * Ii;

// ---- workspace layout (floats) ----
// uints [0,1024): gbar leaf ctrs (32 @ stride 32); uint 2048: root; [4096,5120): leaf gen flags
// uints [8192, 8192+160*32): counters @ stride 32:
//   PROD_A 0-31 | PROD_B 32-63 | PROD_C 64-71 | PROD_X 72-79 | FIN_A 96-127 | FIN_B 128-159
constexpr int OFF_G  = 16384;                 // gates σ'd [4][64][512]
constexpr int OFF_F  = OFF_G + 4 * BbHd;      // F0 = z σ'd; F1 = R·H
constexpr int OFF_HB = OFF_F + 2 * BbHd;      // H double buffer
constexpr int OFF_XB = OFF_HB + 2 * BbHd;     // X-mixed double buffer
constexpr int OFF_PA = OFF_XB + 2 * BbIi;     // A partials: 512 slabs × 4096
constexpr int OFF_PB = OFF_PA + 512 * 4096;   // B partials: 512 slabs × 2048
constexpr int OFF_PC = OFF_PA;                // C partials alias PA slabs 0-127 (FIN_A-gated)
constexpr int OFF_PX = OFF_PA + 128 * 4096;   // X partials alias PA slabs 128.. (FIN_A-gated)
// end = 3,457,024 floats = 13.2 MiB

constexpr int EF = 7872;                      // per-engine LDS floats (48*36 + 48*128)
#define SMEM_BYTES (2 * EF * 4 + 32)

struct P {
  const float *tt, *mark;
  const float *Wxz_t, *Wxr_t, *Wxz_m, *Wxr_m, *Wxh;
  const float *Whz_t, *Whr_t, *Whz_m, *Whr_m, *Whh;
  const float *bz_t, *br_t, *bz_m, *br_m, *bh;
  const float *fWrt, *fWrm, *fWzt, *fWzm, *fWxt, *fWxm;
  const float *frb, *fzb, *fxb;
  float* out; float* ws;
};

enum { JA = 0, JB = 1, JCH = 2, JX = 3 };

DEV float sig1(float x) { return 1.f / (1.f + __expf(-x)); }
DEV float tanh1(float x) { return 2.f * sig1(2.f * x) - 1.f; }
DEV float4 ld4(const float* p) { return *(const float4*)p; }

DEV float2 ld2v(const float* p) {
  unsigned long long u = __hip_atomic_load((const unsigned long long*)p,
                                           __ATOMIC_RELAXED, __HIP_MEMORY_SCOPE_AGENT);
  return __builtin_bit_cast(float2, u);
}
DEV void st2v(float* p, float2 v) {
  __hip_atomic_store((unsigned long long*)p, __builtin_bit_cast(unsigned long long, v),
                     __ATOMIC_RELAXED, __HIP_MEMORY_SCOPE_AGENT);
}
DEV float4 ld4v(const float* p) {
  float2 a = ld2v(p), b = ld2v(p + 2);
  return make_float4(a.x, a.y, b.x, b.y);
}

DEV unsigned* ctr(float* ws, int idx) { return (unsigned*)ws + 8192 + idx * 32; }
DEV void cpoll(unsigned* c, unsigned tgt) {
  while (__hip_atomic_load(c, __ATOMIC_RELAXED, __HIP_MEMORY_SCOPE_AGENT) < tgt)
    __builtin_amdgcn_s_sleep(1);
}

// ---- engine barrier: 4 waves of one 256-thread engine, LDS counter ----
DEV void ebar(unsigned* c, unsigned& tgt) {
  tgt += 4;
  asm volatile("s_waitcnt vmcnt(0) lgkmcnt(0)" ::: "memory");
  if ((threadIdx.x & 63) == 0)
    __hip_atomic_fetch_add(c, 1u, __ATOMIC_RELAXED, __HIP_MEMORY_SCOPE_WORKGROUP);
  while (__hip_atomic_load(c, __ATOMIC_ACQUIRE, __HIP_MEMORY_SCOPE_WORKGROUP) < tgt) {}
}

DEV void tile_wait(float* ws, int idx, unsigned target, unsigned* ebc, unsigned& ebt) {
  ebar(ebc, ebt);                       // all 4 waves vmcnt-drained before bump
  if ((threadIdx.x & 255) == 0) {
    unsigned* c = ctr(ws, idx);
    __hip_atomic_fetch_add(c, 1u, __ATOMIC_RELAXED, __HIP_MEMORY_SCOPE_AGENT);
    cpoll(c, target);
  }
  ebar(ebc, ebt);
}
DEV void fin_wait(float* ws, int idx, unsigned target, unsigned* ebc, unsigned& ebt) {
  if ((threadIdx.x & 255) == 0) cpoll(ctr(ws, idx), target);
  ebar(ebc, ebt);
}
DEV void fin_bump(float* ws, int idx, unsigned* ebc, unsigned& ebt) {
  ebar(ebc, ebt);                       // drain stores first
  if ((threadIdx.x & 255) == 0)
    __hip_atomic_fetch_add(ctr(ws, idx), 1u, __ATOMIC_RELAXED, __HIP_MEMORY_SCOPE_AGENT);
}

template<int S, int STR>
DEV float2 redsum(const float* part, int e0) {
  float2 s = make_float2(0.f, 0.f);
  #pragma unroll
  for (int q = 0; q < S; ++q) {
    float2 v = ld2v(part + q * STR + e0);
    s.x += v.x; s.y += v.y;
  }
  return s;
}

template<int TYPE>
DEV float4 loadA4(const P& p, int t, const float* aux, int side, int b, int k) {
  const float* ws = p.ws;
  if constexpr (TYPE == JA) {          // [X_raw(256) | H(t-1)(512)]
    if (k < Ii) return ld4(&aux[(b * Tt + (t - 1)) * Ii + k]);
    return ld4v(ws + OFF_HB + ((t - 1) & 1) * BbHd + b * Hd + (k - Ii));
  } else if constexpr (TYPE == JB) {   // [Zt|Zm] or [Rt|Rm] σ'd finals
    const int g = (k < Hd) ? side : side + 2;
    const int j = (k < Hd) ? k : k - Hd;
    return ld4v(ws + OFF_G + g * BbHd + b * Hd + j);
  } else if constexpr (TYPE == JCH) {  // [X_mixed(256) | R·H(512)]
    if (k < Ii) return ld4v(ws + OFF_XB + (t & 1) * BbIi + b * Ii + k);
    return ld4v(ws + OFF_F + BbHd + b * Hd + (k - Ii));
  } else {                             // JX: [Xt_raw | Xm_raw] row t
    if (k < Ii) return ld4(&p.tt[(b * Tt + t) * Ii + k]);
    return ld4(&p.mark[(b * Tt + t) * Ii + (k - Ii)]);
  }
}

// GEMM job: tile [32 x TN], K-chunk [K0,K0+KC). 4 engine-waves split KC; 8xNR/lane;
// serialized LDS reduce (single shard); partial -> slab (coherent).
template<int TYPE, int KC, int TN>
DEV void gemm_job(const P& p, float* sm, unsigned* ebc, unsigned& ebt, int t,
                  const float* aux, int side, int brow0, int n0, int K0,
                  const float* wA, int sA, const float* wB, int sB, int kSpl,
                  float* partSlab) {
  constexpr int NR = TN / 16;
  float* ldsA = sm;                    // [KC][36]
  float* ldsW = sm + KC * 36;          // [KC][TN]
  const int etid = threadIdx.x & 255;
  constexpr int kq = KC >> 2;
  for (int idx = etid; idx < (kq << 5); idx += 256) {
    const int m = idx / kq, k4 = idx - m * kq;
    const int k = K0 + (k4 << 2);
    float4 av = loadA4<TYPE>(p, t, aux, side, brow0 + m, k);
    float* d = &ldsA[(k4 << 2) * 36 + m];
    d[0] = av.x; d[36] = av.y; d[72] = av.z; d[108] = av.w;
  }
  constexpr int WQ = TN >> 2;
  for (int idx = etid; idx < KC * WQ; idx += 256) {
    const int kk = idx / WQ, nj = (idx - kk * WQ) << 2;
    const int k = K0 + kk, n = n0 + nj;
    float4 wv = (k < kSpl) ? ld4(&wA[k * sA + n]) : ld4(&wB[(k - kSpl) * sB + n]);
    *(float4*)&ldsW[kk * TN + nj] = wv;
  }
  ebar(ebc, ebt);
  const int wv_ = (threadIdx.x >> 6) & 3, lane = threadIdx.x & 63;
  const int mg = lane >> 4, ng = lane & 15;
  float acc[8][NR];
  #pragma unroll
  for (int i = 0; i < 8; ++i)
    #pragma unroll
    for (int j = 0; j < NR; ++j) acc[i][j] = 0.f;
  constexpr int kcw = KC >> 2;
  for (int kk = wv_ * kcw, ke = wv_ * kcw + kcw; kk < ke; ++kk) {
    float4 a0 = ld4(&ldsA[kk * 36 + (mg << 3)]);
    float4 a1 = ld4(&ldsA[kk * 36 + (mg << 3) + 4]);
    const float am[8] = {a0.x,a0.y,a0.z,a0.w,a1.x,a1.y,a1.z,a1.w};
    float wn[NR];
    float4 w0 = ld4(&ldsW[kk * TN + ng * NR]);
    wn[0] = w0.x; wn[1] = w0.y; wn[2] = w0.z; wn[3] = w0.w;
    if constexpr (NR == 8) {
      float4 w1 = ld4(&ldsW[kk * TN + ng * NR + 4]);
      wn[4] = w1.x; wn[5] = w1.y; wn[6] = w1.z; wn[7] = w1.w;
    }
    #pragma unroll
    for (int mi = 0; mi < 8; ++mi)
      #pragma unroll
      for (int ni = 0; ni < NR; ++ni)
        acc[mi][ni] = fmaf(am[mi], wn[ni], acc[mi][ni]);
  }
  ebar(ebc, ebt);
  constexpr int RS = TN + 4;
  float* red = sm;                      // [32][RS] aliases staging (fits in EF)
  #pragma unroll
  for (int w = 0; w < 4; ++w) {
    if (wv_ == w) {
      #pragma unroll
      for (int mi = 0; mi < 8; ++mi) {
        float* q = &red[((mg << 3) + mi) * RS + ng * NR];
        if (w == 0) {
          *(float4*)q = make_float4(acc[mi][0], acc[mi][1], acc[mi][2], acc[mi][3]);
          if constexpr (NR == 8)
            *(float4*)(q + 4) = make_float4(acc[mi][4], acc[mi][5], acc[mi][6], acc[mi][7]);
        } else {
          float4 c0 = ld4(q);
          *(float4*)q = make_float4(c0.x + acc[mi][0], c0.y + acc[mi][1],
                                    c0.z + acc[mi][2], c0.w + acc[mi][3]);
          if constexpr (NR == 8) {
            float4 c1 = ld4(q + 4);
            *(float4*)(q + 4) = make_float4(c1.x + acc[mi][4], c1.y + acc[mi][5],
                                            c1.z + acc[mi][6], c1.w + acc[mi][7]);
          }
        }
      }
    }
    ebar(ebc, ebt);
  }
  for (int i = etid; i < 16 * TN; i += 256) {   // 32*TN floats = 16*TN float2
    const int el = i * 2, row = el / TN, c = el - row * TN;
    st2v(partSlab + el, make_float2(red[row * RS + c], red[row * RS + c + 1]));
  }
}

// X-mix job (used in prologue and phase C), ex in [0,64)
DEV void xjob(const P& p, float* sm, unsigned* ebc, unsigned& ebt, float* ws,
              int ex, int t, unsigned prodTgt, unsigned aliasTgt) {
  const int ks = ex & 7, tile = ex >> 3;
  const int Mt = tile & 1, NtX = tile >> 1, n0 = NtX * 64;
  if (aliasTgt) fin_wait(ws, 96 + 8 + (ex >> 5), aliasTgt, ebc, ebt);  // PX aliases A tiles 8,9
  gemm_job<JX, 64, 64>(p, sm, ebc, ebt, t, nullptr, 0, Mt * 32, n0, ks * 64,
                       p.fWxt, Ii, p.fWxm, Ii, Ii, ws + OFF_PX + ex * 2048);
  tile_wait(ws, 72 + tile, prodTgt, ebc, ebt);
  const int etid = threadIdx.x & 255;
  if (etid < 128) {
    const int e2 = ks * 256 + etid * 2;
    float2 s = redsum<8, 2048>(ws + OFF_PX + tile * (8 * 2048), e2);
    const int row = e2 >> 6, c6 = e2 & 63, col = n0 + c6, brow = Mt * 32 + row;
    float2 bv = *(const float2*)&p.fxb[col];
    float g0 = sig1(s.x + bv.x), g1 = sig1(s.y + bv.y);
    float2 xt = *(const float2*)&p.tt[(brow * Tt + t) * Ii + col];
    float2 xm = *(const float2*)&p.mark[(brow * Tt + t) * Ii + col];
    st2v(ws + OFF_XB + ((t + 1) & 1) * BbIi + brow * Ii + col,
         make_float2(g0 * xt.x + (1.f - g0) * xm.x, g1 * xt.y + (1.f - g1) * xm.y));
  }
}

// end-of-step grid barrier (decontended tree, round-5/6 form; 512-thread blocks)
DEV void gbar(float* ws, int wg, unsigned tgt) {
  __syncthreads();
  if (threadIdx.x == 0) {
    asm volatile("s_waitcnt vmcnt(0)" ::: "memory");
    unsigned* base = (unsigned*)ws;
    unsigned* leaf = base + (wg >> 3) * 32;
    unsigned* root = base + 2048;
    unsigned* lgen = base + 4096 + (wg >> 3) * 32;
    unsigned a = __hip_atomic_fetch_add(leaf, 1u, __ATOMIC_RELAXED, __HIP_MEMORY_SCOPE_AGENT);
    if ((a & 7u) == 7u) {
      unsigned r = __hip_atomic_fetch_add(root, 1u, __ATOMIC_RELAXED, __HIP_MEMORY_SCOPE_AGENT);
      if ((r & 31u) == 31u) {
        #pragma unroll 4
        for (int i = 0; i < 32; ++i)
          __hip_atomic_store(base + 4096 + i * 32, tgt, __ATOMIC_RELAXED, __HIP_MEMORY_SCOPE_AGENT);
      }
    }
    while (__hip_atomic_load(lgen, __ATOMIC_RELAXED, __HIP_MEMORY_SCOPE_AGENT) < tgt)
      __builtin_amdgcn_s_sleep(1);
  }
  __syncthreads();
}

__global__ void ggru_init(float* ws) {
  const int i = blockIdx.x * 256 + threadIdx.x;
  if (i < 16384) ws[i] = 0.f;                        // barrier + flags + counters
  const int j = i - 16384;
  if (j >= 0 && j < BbHd) ws[OFF_HB + j] = 0.f;      // H0 = 0
}

__global__ __launch_bounds__(NTHR)
void ggru_persist(P p) {
  extern __shared__ float smem[];
  const int wg = blockIdx.x, half = threadIdx.x >> 8, etid = threadIdx.x & 255;
  const int e = (half << 8) | wg;                    // engine id 0..511
  float* sm = smem + half * EF;
  unsigned* ebc = (unsigned*)(smem + 2 * EF) + half;
  unsigned ebt = 0;
  float* ws = p.ws;
  if (threadIdx.x < 2) ((unsigned*)(smem + 2 * EF))[threadIdx.x] = 0u;
  __syncthreads();

  // ---------- prologue: X-mix for step 1 (input row 0) ----------
  if (e < 64) xjob(p, sm, ebc, ebt, ws, e, 0, 8u, 0u);
  gbar(ws, wg, 1u);

  for (int t = 1; t <= Tt; ++t) {
    // ---------- phase A: 4 gate pre-acts (32 tiles x 16 slabs, KC=48, TN=128) ----------
    {
      const int tile = e >> 4, ks = e & 15;
      const int Mt = tile & 1, q = tile >> 1, gate = q >> 2, NtA = q & 3, n0 = NtA * 128;
      const float* wx = gate==0 ? p.Wxz_t : gate==1 ? p.Wxr_t : gate==2 ? p.Wxz_m : p.Wxr_m;
      const float* wh = gate==0 ? p.Whz_t : gate==1 ? p.Whr_t : gate==2 ? p.Whz_m : p.Whr_m;
      const float* xin = (gate < 2) ? p.tt : p.mark;
      gemm_job<JA, 48, 128>(p, sm, ebc, ebt, t, xin, 0, Mt * 32, n0, ks * 48,
                            wx, Hd, wh, Hd, Ii, ws + OFF_PA + e * 4096);
      tile_wait(ws, tile, 16u * (unsigned)t, ebc, ebt);
      if (etid < 128) {
        const int e2 = ks * 256 + etid * 2;
        float2 s = redsum<16, 4096>(ws + OFF_PA + tile * (16 * 4096), e2);
        const int row = e2 >> 7, c = e2 & 127, col = n0 + c, brow = Mt * 32 + row;
        const float* bias = gate==0 ? p.bz_t : gate==1 ? p.br_t : gate==2 ? p.bz_m : p.br_m;
        float2 bv = *(const float2*)&bias[col];
        st2v(ws + OFF_G + gate * BbHd + brow * Hd + col,
             make_float2(sig1(s.x + bv.x), sig1(s.y + bv.y)));
      }
      fin_bump(ws, 96 + tile, ebc, ebt);
    }
    // ---------- phase B: fused z/r (32 tiles x 16 slabs, KC=64, TN=64) ----------
    {
      const int tile = e >> 4, ks = e & 15;
      const int Mt = tile & 1, Nt = tile >> 1, sd = Nt >> 3, Ntl = Nt & 7, n0 = Ntl * 64;
      const int gA = (ks < 8) ? sd : sd + 2;
      fin_wait(ws, 96 + ((gA * 4 + ((ks & 7) >> 1)) * 2 + Mt), 16u * (unsigned)t, ebc, ebt);
      const float* wa = sd ? p.fWrt : p.fWzt;
      const float* wb = sd ? p.fWrm : p.fWzm;
      gemm_job<JB, 64, 64>(p, sm, ebc, ebt, t, nullptr, sd, Mt * 32, n0, ks * 64,
                           wa, Hd, wb, Hd, Hd, ws + OFF_PB + e * 2048);
      tile_wait(ws, 32 + tile, 16u * (unsigned)t, ebc, ebt);
      if (etid < 64) {
        const int e2 = ks * 128 + etid * 2;
        float2 s = redsum<16, 2048>(ws + OFF_PB + tile * (16 * 2048), e2);
        const int row = e2 >> 6, c6 = e2 & 63, col = n0 + c6;
        const int base = (Mt * 32 + row) * Hd + col;
        const float* bias = sd ? p.frb : p.fzb;
        float2 bv = *(const float2*)&bias[col];
        float2 g = make_float2(sig1(s.x + bv.x), sig1(s.y + bv.y));
        if (sd == 0) {
          st2v(ws + OFF_F + base, g);                // z
        } else {                                     // R·H (G1/G3 visible via PROD_B transitivity)
          float2 rt = ld2v(ws + OFF_G + 1 * BbHd + base);
          float2 rm = ld2v(ws + OFF_G + 3 * BbHd + base);
          float2 ho = ld2v(ws + OFF_HB + ((t - 1) & 1) * BbHd + base);
          st2v(ws + OFF_F + BbHd + base,
               make_float2((g.x * rt.x + (1.f - g.x) * rm.x) * ho.x,
                           (g.y * rt.y + (1.f - g.y) * rm.y) * ho.y));
        }
      }
      fin_bump(ws, 128 + tile, ebc, ebt);
    }
    // ---------- phase C: H-tilde + epilogue (8 tiles x 16 slabs) | X-mix(t+1) ----------
    if (e < 128) {
      const int tile = e >> 4, ks = e & 15;
      const int Mt = tile & 1, NtC = tile >> 1, n0 = NtC * 128;
      if (etid == 0) {
        cpoll(ctr(ws, 96 + tile), 16u * (unsigned)t);           // alias: PC uses A-tile 'tile' slabs
        const int lo = ks * 48, hi = lo + 48;
        if (hi > 256) {
          const int lo2 = lo > 256 ? lo : 256;
          const int b0 = (lo2 - 256) >> 6, b1 = (hi - 1 - 256) >> 6;
          for (int b = b0; b <= b1; ++b)
            cpoll(ctr(ws, 128 + ((8 + b) * 2 + Mt)), 16u * (unsigned)t);   // R·H r-tiles
        }
      }
      ebar(ebc, ebt);
      gemm_job<JCH, 48, 128>(p, sm, ebc, ebt, t, nullptr, 0, Mt * 32, n0, ks * 48,
                             p.Wxh, Hd, p.Whh, Hd, Ii, ws + OFF_PC + e * 4096);
      tile_wait(ws, 64 + tile, 16u * (unsigned)t, ebc, ebt);
      if (etid == 0) {
        cpoll(ctr(ws, 128 + ((NtC * 2) * 2 + Mt)),     16u * (unsigned)t);  // z tiles
        cpoll(ctr(ws, 128 + ((NtC * 2 + 1) * 2 + Mt)), 16u * (unsigned)t);
        cpoll(ctr(ws, 96 + ((0 + NtC) * 2 + Mt)),      16u * (unsigned)t);  // G0 tile
        cpoll(ctr(ws, 96 + ((8 + NtC) * 2 + Mt)),      16u * (unsigned)t);  // G2 tile
      }
      ebar(ebc, ebt);
      if (etid < 128) {
        const int e2 = ks * 256 + etid * 2;
        float2 s = redsum<16, 4096>(ws + OFF_PC + tile * (16 * 4096), e2);
        const int row = e2 >> 7, c = e2 & 127, col = n0 + c;
        const int brow = Mt * 32 + row, base = brow * Hd + col;
        float2 bv = *(const float2*)&p.bh[col];
        float ht0 = tanh1(s.x + bv.x), ht1 = tanh1(s.y + bv.y);
        float2 zf = ld2v(ws + OFF_F + base);
        float2 zt = ld2v(ws + OFF_G + base);
        float2 zm = ld2v(ws + OFF_G + 2 * BbHd + base);
        float2 ho = ld2v(ws + OFF_HB + ((t - 1) & 1) * BbHd + base);
        float Z0 = zf.x * zt.x + (1.f - zf.x) * zm.x;
        float Z1 = zf.y * zt.y + (1.f - zf.y) * zm.y;
        float2 hn = make_float2(Z0 * ho.x + (1.f - Z0) * ht0, Z1 * ho.y + (1.f - Z1) * ht1);
        st2v(ws + OFF_HB + (t & 1) * BbHd + base, hn);
        *(float2*)&p.out[(brow * Tt + (t - 1)) * Hd + col] = hn;
        if (t == Tt) *(float2*)&p.out[Bb * Tt * Hd + brow * Hd + col] = hn;
      }
    } else if (e < 192 && t < Tt) {
      xjob(p, sm, ebc, ebt, ws, e - 128, t, 8u * (unsigned)(t + 1), 16u * (unsigned)t);
    }
    gbar(ws, wg, (unsigned)(t + 1));
  }
}

extern "C" void kernel_launch(void* const* d_in, const int* in_sizes, int n_in,
                              void* d_out, int out_size, void* d_ws, size_t ws_size,
                              hipStream_t stream) {
  P pr;
  pr.tt    = (const float*)d_in[0];
  pr.mark  = (const float*)d_in[1];
  pr.Wxz_t = (const float*)d_in[2];
  pr.Wxr_t = (const float*)d_in[3];
  pr.Wxz_m = (const float*)d_in[4];
  pr.Wxr_m = (const float*)d_in[5];
  pr.Wxh   = (const float*)d_in[6];
  pr.Whz_t = (const float*)d_in[7];
  pr.Whr_t = (const float*)d_in[8];
  pr.Whz_m = (const float*)d_in[9];
  pr.Whr_m = (const float*)d_in[10];
  pr.Whh   = (const float*)d_in[11];
  pr.bz_t  = (const float*)d_in[12];
  pr.br_t  = (const float*)d_in[13];
  pr.bz_m  = (const float*)d_in[14];
  pr.br_m  = (const float*)d_in[15];
  pr.bh    = (const float*)d_in[16];
  pr.fWrt  = (const float*)d_in[17];
  pr.fWrm  = (const float*)d_in[18];
  pr.fWzt  = (const float*)d_in[19];
  pr.fWzm  = (const float*)d_in[20];
  pr.fWxt  = (const float*)d_in[21];
  pr.fWxm  = (const float*)d_in[22];
  pr.frb   = (const float*)d_in[23];
  pr.fzb   = (const float*)d_in[24];
  pr.fxb   = (const float*)d_in[25];
  pr.out = (float*)d_out;
  pr.ws  = (float*)d_ws;

  hipLaunchKernelGGL(ggru_init, dim3(192), dim3(256), 0, stream, (float*)d_ws);

  void* args[] = { (void*)&pr };
  hipError_t err = hipLaunchCooperativeKernel((const void*)ggru_persist,
                                              dim3(NWG), dim3(NTHR),
                                              args, (unsigned)SMEM_BYTES, stream);
  if (err != hipSuccess) {
    hipLaunchKernelGGL(ggru_persist, dim3(NWG), dim3(NTHR), SMEM_BYTES, stream, pr);
  }
}

// Round 8
// 23454.425 us; speedup vs baseline: 1.8456x; 1.8456x over previous
//
#include <hip/hip_runtime.h>

#define DEV __device__ __forceinline__

constexpr int Bb = 64, Tt = 512, Ii = 256, Hd = 512;
constexpr int NWG = 256, NTHR = 256;
constexpr int BbHd = Bb * Hd, BbIi = Bb * Ii;

// ---- workspace layout (floats) ----
// [0,16384): sync region — uints: leaf ctrs [0..1024) @32-stride, root @2048,
//            per-leaf gen flags @4096+i*32 (round-5 decontended gbar, proven)
constexpr int OFF_G  = 16384;                 // gates σ'd [4][64][512]
constexpr int OFF_F  = OFF_G + 4 * BbHd;      // F0 = z σ'd; F1 = R·H
constexpr int OFF_HB = OFF_F + 2 * BbHd;      // H double buffer [2][64][512]
constexpr int OFF_XB = OFF_HB + 2 * BbHd;     // X-mixed ring [2][64][256]
constexpr int OFF_AH = OFF_XB + 2 * BbIi;     // Ah preact ring [2][64][512]
// end = 376832 floats = 1.47 MB — no partial buffers at all

#define SMEM_BYTES 16384                      // max(ldsA 4*1024, red 8*512) floats * 4B

struct P {
  const float *tt, *mark;
  const float *Wxz_t, *Wxr_t, *Wxz_m, *Wxr_m, *Wxh;
  const float *Whz_t, *Whr_t, *Whz_m, *Whr_m, *Whh;
  const float *bz_t, *br_t, *bz_m, *br_m, *bh;
  const float *fWrt, *fWrm, *fWzt, *fWzm, *fWxt, *fWxm;
  const float *frb, *fzb, *fxb;
  float* out; float* ws;
};

enum { JA = 0, JB = 1, JRH = 2, JX = 3, JXB = 4 };

DEV float sig1(float x) { return 1.f / (1.f + __expf(-x)); }
DEV float tanh1(float x) { return 2.f * sig1(2.f * x) - 1.f; }
DEV float4 ld4(const float* p) { return *(const float4*)p; }

// coherent (agent-scope, L2-bypass) 8B load/store
DEV float2 ld2v(const float* p) {
  unsigned long long u = __hip_atomic_load((const unsigned long long*)p,
                                           __ATOMIC_RELAXED, __HIP_MEMORY_SCOPE_AGENT);
  return __builtin_bit_cast(float2, u);
}
DEV void st2v(float* p, float2 v) {
  __hip_atomic_store((unsigned long long*)p, __builtin_bit_cast(unsigned long long, v),
                     __ATOMIC_RELAXED, __HIP_MEMORY_SCOPE_AGENT);
}
DEV float4 ld4v(const float* p) {
  float2 a = ld2v(p), b = ld2v(p + 2);
  return make_float4(a.x, a.y, b.x, b.y);
}

// A-operand generator for 4 consecutive k (groups never straddle segment bounds)
template<int TYPE>
DEV float4 loadA4(const P& p, int t, const float* aux, int side, int b, int k) {
  const float* ws = p.ws;
  if constexpr (TYPE == JA) {          // [X_raw row t-1 (256) | H(t-1) (512)]
    if (k < Ii) return ld4(&aux[(b * Tt + (t - 1)) * Ii + k]);
    return ld4v(ws + OFF_HB + ((t - 1) & 1) * BbHd + b * Hd + (k - Ii));
  } else if constexpr (TYPE == JB) {   // [Zt|Zm] (side0) or [Rt|Rm] (side1)
    const int g = (k < Hd) ? side : side + 2;
    const int j = (k < Hd) ? k : k - Hd;
    return ld4v(ws + OFF_G + g * BbHd + b * Hd + j);
  } else if constexpr (TYPE == JRH) {  // R·H (512)
    return ld4v(ws + OFF_F + BbHd + b * Hd + k);
  } else if constexpr (TYPE == JX) {   // [Xt_raw | Xm_raw] row t (for step t+1)
    if (k < Ii) return ld4(&p.tt[(b * Tt + t) * Ii + k]);
    return ld4(&p.mark[(b * Tt + t) * Ii + (k - Ii)]);
  } else {                             // JXB: X_mixed(t+1) ring (256)
    return ld4v(ws + OFF_XB + ((t + 1) & 1) * BbIi + b * Ii + k);
  }
}

DEV void fma32(float (&acc)[4][4], const float2 (&a)[4], float4 w0, float4 w1) {
  const float wx[4] = {w0.x, w0.y, w0.z, w0.w};
  const float wy[4] = {w1.x, w1.y, w1.z, w1.w};
  #pragma unroll
  for (int m = 0; m < 4; ++m)
    #pragma unroll
    for (int c = 0; c < 4; ++c)
      acc[m][c] = fmaf(a[m].y, wy[c], fmaf(a[m].x, wx[c], acc[m][c]));
}

// Full-K GEMM job: out tile [4 x 128] at (rb*4, n0). A staged in LDS once; weights
// streamed from L2 (coalesced ld4, no LDS); 8 k-stripes in registers; LDS reduce.
// Returns this thread's float2 of the output tile (elem e = tid*2).
template<int TYPE, int K, int KSPL>
DEV float2 jobcore(const P& p, float* lds, int t, const float* aux, int side,
                   int rb, int n0, const float* wA, int sA, const float* wB, int sB) {
  const int tid = threadIdx.x;
  constexpr int Kq = K / 4;
  for (int idx = tid; idx < 4 * Kq; idx += NTHR) {
    const int r = idx / Kq, i4 = idx - r * Kq;
    float4 v = loadA4<TYPE>(p, t, aux, side, rb * 4 + r, i4 * 4);
    *(float4*)&lds[r * K + i4 * 4] = v;
  }
  __syncthreads();
  const int kk = tid >> 5, nq = tid & 31, nb = n0 + nq * 4;
  float acc[4][4] = {};
  float2 a[4];
  #pragma unroll 4
  for (int i2 = 0; i2 < KSPL / 16; ++i2) {
    const int k = i2 * 16 + kk * 2;
    float4 w0 = ld4(&wA[k * sA + nb]);
    float4 w1 = ld4(&wA[(k + 1) * sA + nb]);
    a[0] = *(const float2*)&lds[0 * K + k];
    a[1] = *(const float2*)&lds[1 * K + k];
    a[2] = *(const float2*)&lds[2 * K + k];
    a[3] = *(const float2*)&lds[3 * K + k];
    fma32(acc, a, w0, w1);
  }
  #pragma unroll 4
  for (int i2 = KSPL / 16; i2 < K / 16; ++i2) {
    const int k = i2 * 16 + kk * 2;
    float4 w0 = ld4(&wB[(k - KSPL) * sB + nb]);
    float4 w1 = ld4(&wB[(k - KSPL + 1) * sB + nb]);
    a[0] = *(const float2*)&lds[0 * K + k];
    a[1] = *(const float2*)&lds[1 * K + k];
    a[2] = *(const float2*)&lds[2 * K + k];
    a[3] = *(const float2*)&lds[3 * K + k];
    fma32(acc, a, w0, w1);
  }
  __syncthreads();                 // everyone done reading ldsA; alias as red
  float* red = lds;                // red[kk][m][128]
  #pragma unroll
  for (int m = 0; m < 4; ++m)
    *(float4*)&red[kk * 512 + m * 128 + nq * 4] =
        make_float4(acc[m][0], acc[m][1], acc[m][2], acc[m][3]);
  __syncthreads();
  const int e = tid * 2;
  float2 s = make_float2(0.f, 0.f);
  #pragma unroll
  for (int q = 0; q < 8; ++q) {
    float2 v = *(const float2*)&red[q * 512 + e];
    s.x += v.x; s.y += v.y;
  }
  return s;
}

// round-5 decontended grid barrier (proven), unchanged
DEV void gbar(float* ws, int wg, unsigned tgt) {
  __syncthreads();
  if (threadIdx.x == 0) {
    asm volatile("s_waitcnt vmcnt(0)" ::: "memory");
    unsigned* base = (unsigned*)ws;
    unsigned* leaf = base + (wg >> 3) * 32;
    unsigned* root = base + 2048;
    unsigned* lgen = base + 4096 + (wg >> 3) * 32;
    unsigned a = __hip_atomic_fetch_add(leaf, 1u, __ATOMIC_RELAXED, __HIP_MEMORY_SCOPE_AGENT);
    if ((a & 7u) == 7u) {
      unsigned r = __hip_atomic_fetch_add(root, 1u, __ATOMIC_RELAXED, __HIP_MEMORY_SCOPE_AGENT);
      if ((r & 31u) == 31u) {
        #pragma unroll 4
        for (int i = 0; i < 32; ++i)
          __hip_atomic_store(base + 4096 + i * 32, tgt, __ATOMIC_RELAXED, __HIP_MEMORY_SCOPE_AGENT);
      }
    }
    while (__hip_atomic_load(lgen, __ATOMIC_RELAXED, __HIP_MEMORY_SCOPE_AGENT) < tgt)
      __builtin_amdgcn_s_sleep(1);
  }
  __syncthreads();
}

__global__ void ggru_init(float* ws) {
  const int i = blockIdx.x * 256 + threadIdx.x;
  if (i < 16384) ws[i] = 0.f;                       // sync region
  const int j = i - 16384;
  if (j >= 0 && j < BbHd) ws[OFF_HB + j] = 0.f;     // H0 = 0 (buffer 0)
}

__global__ __launch_bounds__(NTHR)
void ggru_persist(P p) {
  extern __shared__ float sm[];
  const int wg = blockIdx.x, tid = threadIdx.x;
  float* ws = p.ws;
  unsigned bt = 0;

  // ---------- prologue P0: X-mix(1) from raw row 0 -> XB[1] ----------
  if (wg < 32) {
    const int rb = wg >> 1, n0 = (wg & 1) * 128;
    float2 s = jobcore<JX, 512, 256>(p, sm, 0, nullptr, 0, rb, n0, p.fWxt, Ii, p.fWxm, Ii);
    const int e = tid * 2, brow = rb * 4 + (e >> 7), col = n0 + (e & 127);
    float2 bv = *(const float2*)&p.fxb[col];
    float g0 = sig1(s.x + bv.x), g1 = sig1(s.y + bv.y);
    float2 xt = *(const float2*)&p.tt[(brow * Tt + 0) * Ii + col];
    float2 xm = *(const float2*)&p.mark[(brow * Tt + 0) * Ii + col];
    st2v(ws + OFF_XB + 1 * BbIi + brow * Ii + col,
         make_float2(g0 * xt.x + (1.f - g0) * xm.x, g1 * xt.y + (1.f - g1) * xm.y));
  }
  gbar(ws, wg, ++bt);
  // ---------- prologue P1: Ah(1) = X_mixed(1) @ Wxh -> AH[1] ----------
  if (wg < 64) {
    const int rb = wg >> 2, n0 = (wg & 3) * 128;
    float2 s = jobcore<JXB, 256, 256>(p, sm, 0, nullptr, 0, rb, n0, p.Wxh, Hd, p.Wxh, Hd);
    const int e = tid * 2, brow = rb * 4 + (e >> 7), col = n0 + (e & 127);
    st2v(ws + OFF_AH + 1 * BbHd + brow * Hd + col, s);
  }
  gbar(ws, wg, ++bt);

  for (int t = 1; t <= Tt; ++t) {
    // ---------- phase A: 4 gate GEMMs, full K=768, 256 jobs ----------
    {
      const int rb = wg >> 4, q = wg & 15, gate = q >> 2, n0 = (q & 3) * 128;
      const float* wx = gate==0 ? p.Wxz_t : gate==1 ? p.Wxr_t : gate==2 ? p.Wxz_m : p.Wxr_m;
      const float* wh = gate==0 ? p.Whz_t : gate==1 ? p.Whr_t : gate==2 ? p.Whz_m : p.Whr_m;
      const float* xin = (gate < 2) ? p.tt : p.mark;
      float2 s = jobcore<JA, 768, 256>(p, sm, t, xin, 0, rb, n0, wx, Hd, wh, Hd);
      const int e = tid * 2, brow = rb * 4 + (e >> 7), col = n0 + (e & 127);
      const float* bias = gate==0 ? p.bz_t : gate==1 ? p.br_t : gate==2 ? p.bz_m : p.br_m;
      float2 bv = *(const float2*)&bias[col];
      st2v(ws + OFF_G + gate * BbHd + brow * Hd + col,
           make_float2(sig1(s.x + bv.x), sig1(s.y + bv.y)));
    }
    gbar(ws, wg, ++bt);
    // ---------- phase B: fused z/r full K=1024 (128 jobs) | X-mix(t+1) (32) ----------
    if (wg < 128) {
      const int rb = wg >> 3, side = (wg >> 2) & 1, n0 = (wg & 3) * 128;
      const float* wa = side ? p.fWrt : p.fWzt;
      const float* wb = side ? p.fWrm : p.fWzm;
      float2 s = jobcore<JB, 1024, 512>(p, sm, t, nullptr, side, rb, n0, wa, Hd, wb, Hd);
      const int e = tid * 2, brow = rb * 4 + (e >> 7), col = n0 + (e & 127);
      const int base = brow * Hd + col;
      const float* bias = side ? p.frb : p.fzb;
      float2 bv = *(const float2*)&bias[col];
      float2 g = make_float2(sig1(s.x + bv.x), sig1(s.y + bv.y));
      if (side == 0) {
        st2v(ws + OFF_F + base, g);                  // z
      } else {                                       // r -> R·H = (r*Rt+(1-r)*Rm)*H(t-1)
        float2 rt = ld2v(ws + OFF_G + 1 * BbHd + base);
        float2 rm = ld2v(ws + OFF_G + 3 * BbHd + base);
        float2 ho = ld2v(ws + OFF_HB + ((t - 1) & 1) * BbHd + base);
        st2v(ws + OFF_F + BbHd + base,
             make_float2((g.x * rt.x + (1.f - g.x) * rm.x) * ho.x,
                         (g.y * rt.y + (1.f - g.y) * rm.y) * ho.y));
      }
    } else if (wg < 160 && t < Tt) {
      const int j = wg - 128, rb = j >> 1, n0 = (j & 1) * 128;
      float2 s = jobcore<JX, 512, 256>(p, sm, t, nullptr, 0, rb, n0, p.fWxt, Ii, p.fWxm, Ii);
      const int e = tid * 2, brow = rb * 4 + (e >> 7), col = n0 + (e & 127);
      float2 bv = *(const float2*)&p.fxb[col];
      float g0 = sig1(s.x + bv.x), g1 = sig1(s.y + bv.y);
      float2 xt = *(const float2*)&p.tt[(brow * Tt + t) * Ii + col];
      float2 xm = *(const float2*)&p.mark[(brow * Tt + t) * Ii + col];
      st2v(ws + OFF_XB + ((t + 1) & 1) * BbIi + brow * Ii + col,
           make_float2(g0 * xt.x + (1.f - g0) * xm.x, g1 * xt.y + (1.f - g1) * xm.y));
    }
    gbar(ws, wg, ++bt);
    // ---------- phase C: H-tilde K=512 + epilogue (64) | Ah(t+1) K=256 (64) ----------
    if (wg < 64) {
      const int rb = wg >> 2, n0 = (wg & 3) * 128;
      float2 s = jobcore<JRH, 512, 512>(p, sm, t, nullptr, 0, rb, n0, p.Whh, Hd, p.Whh, Hd);
      const int e = tid * 2, brow = rb * 4 + (e >> 7), col = n0 + (e & 127);
      const int base = brow * Hd + col;
      float2 ah = ld2v(ws + OFF_AH + (t & 1) * BbHd + base);
      float2 bv = *(const float2*)&p.bh[col];
      float ht0 = tanh1(s.x + ah.x + bv.x), ht1 = tanh1(s.y + ah.y + bv.y);
      float2 zf = ld2v(ws + OFF_F + base);
      float2 zt = ld2v(ws + OFF_G + base);
      float2 zm = ld2v(ws + OFF_G + 2 * BbHd + base);
      float2 ho = ld2v(ws + OFF_HB + ((t - 1) & 1) * BbHd + base);
      float Z0 = zf.x * zt.x + (1.f - zf.x) * zm.x;
      float Z1 = zf.y * zt.y + (1.f - zf.y) * zm.y;
      float2 hn = make_float2(Z0 * ho.x + (1.f - Z0) * ht0, Z1 * ho.y + (1.f - Z1) * ht1);
      st2v(ws + OFF_HB + (t & 1) * BbHd + base, hn);
      *(float2*)&p.out[(brow * Tt + (t - 1)) * Hd + col] = hn;
      if (t == Tt) *(float2*)&p.out[Bb * Tt * Hd + brow * Hd + col] = hn;
    } else if (wg < 128 && t < Tt) {
      const int j = wg - 64, rb = j >> 2, n0 = (j & 3) * 128;
      float2 s = jobcore<JXB, 256, 256>(p, sm, t, nullptr, 0, rb, n0, p.Wxh, Hd, p.Wxh, Hd);
      const int e = tid * 2, brow = rb * 4 + (e >> 7), col = n0 + (e & 127);
      st2v(ws + OFF_AH + ((t + 1) & 1) * BbHd + brow * Hd + col, s);
    }
    gbar(ws, wg, ++bt);
  }
}

extern "C" void kernel_launch(void* const* d_in, const int* in_sizes, int n_in,
                              void* d_out, int out_size, void* d_ws, size_t ws_size,
                              hipStream_t stream) {
  P pr;
  pr.tt    = (const float*)d_in[0];
  pr.mark  = (const float*)d_in[1];
  pr.Wxz_t = (const float*)d_in[2];
  pr.Wxr_t = (const float*)d_in[3];
  pr.Wxz_m = (const float*)d_in[4];
  pr.Wxr_m = (const float*)d_in[5];
  pr.Wxh   = (const float*)d_in[6];
  pr.Whz_t = (const float*)d_in[7];
  pr.Whr_t = (const float*)d_in[8];
  pr.Whz_m = (const float*)d_in[9];
  pr.Whr_m = (const float*)d_in[10];
  pr.Whh   = (const float*)d_in[11];
  pr.bz_t  = (const float*)d_in[12];
  pr.br_t  = (const float*)d_in[13];
  pr.bz_m  = (const float*)d_in[14];
  pr.br_m  = (const float*)d_in[15];
  pr.bh    = (const float*)d_in[16];
  pr.fWrt  = (const float*)d_in[17];
  pr.fWrm  = (const float*)d_in[18];
  pr.fWzt  = (const float*)d_in[19];
  pr.fWzm  = (const float*)d_in[20];
  pr.fWxt  = (const float*)d_in[21];
  pr.fWxm  = (const float*)d_in[22];
  pr.frb   = (const float*)d_in[23];
  pr.fzb   = (const float*)d_in[24];
  pr.fxb   = (const float*)d_in[25];
  pr.out = (float*)d_out;
  pr.ws  = (float*)d_ws;

  hipLaunchKernelGGL(ggru_init, dim3(192), dim3(256), 0, stream, (float*)d_ws);

  void* args[] = { (void*)&pr };
  hipError_t err = hipLaunchCooperativeKernel((const void*)ggru_persist,
                                              dim3(NWG), dim3(NTHR),
                                              args, (unsigned)SMEM_BYTES, stream);
  if (err != hipSuccess) {
    hipLaunchKernelGGL(ggru_persist, dim3(NWG), dim3(NTHR), SMEM_BYTES, stream, pr);
  }
}

// Round 9
// 17448.035 us; speedup vs baseline: 2.4809x; 1.3442x over previous
//
#include <hip/hip_runtime.h>

#define DEV __device__ __forceinline__

constexpr int Bb = 64, Tt = 512, Ii = 256, Hd = 512;
constexpr int NWG = 256, NTHR = 256;
constexpr int BbHd = Bb * Hd, BbIi = Bb * Ii;

// 8 independent groups × 32 WGs × 8 batch rows. WG wg: g = wg>>5, j = wg&31.
// XCD(wg) = wg%8 = j%8  ->  same j-slice (same weight cols) lands on the same XCD
// for every group => per-XCD weight working set = 12.6MB/8 = 1.6MB, L2-resident.

// ---- workspace layout (floats) ----
// [0,16384): sync — per-group: counter @ uint g*64, gen flag @ uint g*64+32
constexpr int OFF_G  = 16384;                 // gates σ'd [4][64][512]
constexpr int OFF_F  = OFF_G + 4 * BbHd;      // F0 = z σ'd; F1 = R·H
constexpr int OFF_HB = OFF_F + 2 * BbHd;      // H double buffer [2][64][512]
constexpr int OFF_XB = OFF_HB + 2 * BbHd;     // X-mixed ring [2][64][256]
constexpr int OFF_AH = OFF_XB + 2 * BbIi;     // Ah preact ring [2][64][512]
// end = 376832 floats = 1.47 MB

#define SMEM_BYTES 32768                      // staging [8][K<=1024]; red aliases

struct P {
  const float *tt, *mark;
  const float *Wxz_t, *Wxr_t, *Wxz_m, *Wxr_m, *Wxh;
  const float *Whz_t, *Whr_t, *Whz_m, *Whr_m, *Whh;
  const float *bz_t, *br_t, *bz_m, *br_m, *bh;
  const float *fWrt, *fWrm, *fWzt, *fWzm, *fWxt, *fWxm;
  const float *frb, *fzb, *fxb;
  float* out; float* ws;
};

enum { JA = 0, JB = 1, JRH = 2, JX = 3, JXB = 4 };

DEV float sig1(float x) { return 1.f / (1.f + __expf(-x)); }
DEV float tanh1(float x) { return 2.f * sig1(2.f * x) - 1.f; }
DEV float4 ld4(const float* p) { return *(const float4*)p; }

// coherent (agent-scope) 8B load/store
DEV float2 ld2v(const float* p) {
  unsigned long long u = __hip_atomic_load((const unsigned long long*)p,
                                           __ATOMIC_RELAXED, __HIP_MEMORY_SCOPE_AGENT);
  return __builtin_bit_cast(float2, u);
}
DEV void st2v(float* p, float2 v) {
  __hip_atomic_store((unsigned long long*)p, __builtin_bit_cast(unsigned long long, v),
                     __ATOMIC_RELAXED, __HIP_MEMORY_SCOPE_AGENT);
}
DEV float4 ld4v(const float* p) {
  float2 a = ld2v(p), b = ld2v(p + 2);
  return make_float4(a.x, a.y, b.x, b.y);
}

// A-operand: 4 consecutive k (groups never straddle segment bounds). b = absolute row.
template<int TYPE>
DEV float4 loadA4(const P& p, int t, const float* aux, int side, int b, int k) {
  const float* ws = p.ws;
  if constexpr (TYPE == JA) {          // [X_raw row t-1 (256) | H(t-1) (512)]
    if (k < Ii) return ld4(&aux[(b * Tt + (t - 1)) * Ii + k]);
    return ld4v(ws + OFF_HB + ((t - 1) & 1) * BbHd + b * Hd + (k - Ii));
  } else if constexpr (TYPE == JB) {   // [Zt|Zm] (side0) / [Rt|Rm] (side1)
    const int g = (k < Hd) ? side : side + 2;
    const int j = (k < Hd) ? k : k - Hd;
    return ld4v(ws + OFF_G + g * BbHd + b * Hd + j);
  } else if constexpr (TYPE == JRH) {  // R·H (512)
    return ld4v(ws + OFF_F + BbHd + b * Hd + k);
  } else if constexpr (TYPE == JX) {   // [Xt_raw | Xm_raw] row t
    if (k < Ii) return ld4(&p.tt[(b * Tt + t) * Ii + k]);
    return ld4(&p.mark[(b * Tt + t) * Ii + (k - Ii)]);
  } else {                             // JXB: X_mixed(t+1) ring (256)
    return ld4v(ws + OFF_XB + ((t + 1) & 1) * BbIi + b * Ii + k);
  }
}

// Full-K GEMM: out tile [8 rows x NC cols] at (rb, n0). A staged once to LDS; weights
// streamed from XCD-local L2; 512/NC k-stripes; LDS reduce. Thread tid owns output
// elems e=2*tid (valid when e < 8*NC): r=e/NC, c=e%NC (local col).
template<int TYPE, int K, int KSPL, int NC>
DEV float2 job8(const P& p, float* lds, int t, const float* aux, int side, int rb,
                int n0, const float* wA, int sA, const float* wB, int sB) {
  const int tid = threadIdx.x;
  constexpr int Kq = K / 4;
  for (int idx = tid; idx < 8 * Kq; idx += NTHR) {
    const int r = idx / Kq, i4 = (idx - r * Kq) * 4;
    float4 v = loadA4<TYPE>(p, t, aux, side, rb + r, i4);
    *(float4*)&lds[r * K + i4] = v;
  }
  __syncthreads();
  constexpr int TPS = NC / 2;          // threads per k-stripe
  constexpr int S = NTHR / TPS;        // k-stripes
  constexpr int Kper = K / S;
  const int kk = tid / TPS, cq = tid % TPS;
  const int c0 = n0 + 2 * cq;
  const int kbase = kk * Kper;
  float acc[8][2] = {};
  #pragma unroll 2
  for (int i = 0; i < Kper / 2; ++i) {
    const int k = kbase + 2 * i;
    const float* wr0 = (k < KSPL) ? &wA[k * sA] : &wB[(k - KSPL) * sB];
    const float* wr1 = (k + 1 < KSPL) ? &wA[(k + 1) * sA] : &wB[(k + 1 - KSPL) * sB];
    float2 w0 = *(const float2*)&wr0[c0];
    float2 w1 = *(const float2*)&wr1[c0];
    #pragma unroll
    for (int r = 0; r < 8; ++r) {
      float2 a = *(const float2*)&lds[r * K + k];
      acc[r][0] = fmaf(a.y, w1.x, fmaf(a.x, w0.x, acc[r][0]));
      acc[r][1] = fmaf(a.y, w1.y, fmaf(a.x, w0.y, acc[r][1]));
    }
  }
  __syncthreads();
  float* red = lds;                    // [S][8*NC], aliases staging
  #pragma unroll
  for (int r = 0; r < 8; ++r)
    *(float2*)&red[(kk * 8 + r) * NC + 2 * cq] = make_float2(acc[r][0], acc[r][1]);
  __syncthreads();
  float2 s = make_float2(0.f, 0.f);
  const int e = tid * 2;
  if (e < 8 * NC) {
    #pragma unroll
    for (int q = 0; q < S; ++q) {
      float2 v = *(const float2*)&red[q * 8 * NC + e];
      s.x += v.x; s.y += v.y;
    }
  }
  return s;
}

// group barrier: 32 WGs, monotonic target
DEV void grpbar(float* ws, int g, unsigned tgt) {
  __syncthreads();
  if (threadIdx.x == 0) {
    asm volatile("s_waitcnt vmcnt(0)" ::: "memory");
    unsigned* cnt = (unsigned*)ws + g * 64;
    unsigned* gen = (unsigned*)ws + g * 64 + 32;
    unsigned a = __hip_atomic_fetch_add(cnt, 1u, __ATOMIC_RELAXED, __HIP_MEMORY_SCOPE_AGENT);
    if (a == 32u * tgt - 1u)
      __hip_atomic_store(gen, tgt, __ATOMIC_RELAXED, __HIP_MEMORY_SCOPE_AGENT);
    while (__hip_atomic_load(gen, __ATOMIC_RELAXED, __HIP_MEMORY_SCOPE_AGENT) < tgt)
      __builtin_amdgcn_s_sleep(1);
  }
  __syncthreads();
}

__global__ void ggru_init(float* ws) {
  const int i = blockIdx.x * 256 + threadIdx.x;
  if (i < 16384) ws[i] = 0.f;                       // sync region
  const int j = i - 16384;
  if (j >= 0 && j < BbHd) ws[OFF_HB + j] = 0.f;     // H0 = 0 (buffer 0)
}

__global__ __launch_bounds__(NTHR)
void ggru_persist(P p) {
  extern __shared__ float sm[];
  const int wg = blockIdx.x, tid = threadIdx.x;
  const int g = wg >> 5, j = wg & 31, rb = g * 8;   // group, slot, batch-row base
  float* ws = p.ws;
  unsigned bt = 0;
  const int e = tid * 2;

  // ---------- prologue: X-mix(1) then Ah(1) ----------
  if (j < 8) {
    float2 s = job8<JX, 512, 256, 32>(p, sm, 0, nullptr, 0, rb, j * 32, p.fWxt, Ii, p.fWxm, Ii);
    if (tid < 128) {
      const int r = e >> 5, c = e & 31, col = j * 32 + c, brow = rb + r;
      float2 bv = *(const float2*)&p.fxb[col];
      float g0 = sig1(s.x + bv.x), g1 = sig1(s.y + bv.y);
      float2 xt = *(const float2*)&p.tt[(brow * Tt + 0) * Ii + col];
      float2 xm = *(const float2*)&p.mark[(brow * Tt + 0) * Ii + col];
      st2v(ws + OFF_XB + 1 * BbIi + brow * Ii + col,
           make_float2(g0 * xt.x + (1.f - g0) * xm.x, g1 * xt.y + (1.f - g1) * xm.y));
    }
  }
  grpbar(ws, g, ++bt);
  if (j < 8) {
    float2 s = job8<JXB, 256, 256, 64>(p, sm, 0, nullptr, 0, rb, j * 64, p.Wxh, Hd, p.Wxh, Hd);
    const int r = e >> 6, c = e & 63, col = j * 64 + c;
    st2v(ws + OFF_AH + 1 * BbHd + (rb + r) * Hd + col, s);
  }
  grpbar(ws, g, ++bt);

  for (int t = 1; t <= Tt; ++t) {
    // ---------- phase A: 4 gates [8 x 512 each], K=768; all 32 slots ----------
    {
      const int gate = j >> 3, cb = j & 7, n0 = cb * 64;
      const float* wx = gate==0 ? p.Wxz_t : gate==1 ? p.Wxr_t : gate==2 ? p.Wxz_m : p.Wxr_m;
      const float* wh = gate==0 ? p.Whz_t : gate==1 ? p.Whr_t : gate==2 ? p.Whz_m : p.Whr_m;
      const float* xin = (gate < 2) ? p.tt : p.mark;
      float2 s = job8<JA, 768, 256, 64>(p, sm, t, xin, 0, rb, n0, wx, Hd, wh, Hd);
      const int r = e >> 6, c = e & 63, col = n0 + c;
      const float* bias = gate==0 ? p.bz_t : gate==1 ? p.br_t : gate==2 ? p.bz_m : p.br_m;
      float2 bv = *(const float2*)&bias[col];
      st2v(ws + OFF_G + gate * BbHd + (rb + r) * Hd + col,
           make_float2(sig1(s.x + bv.x), sig1(s.y + bv.y)));
    }
    grpbar(ws, g, ++bt);
    // ---------- phase B: z/r K=1024 (16 slots) || X-mix(t+1) (8 slots) ----------
    if (j < 16) {
      const int side = j >> 3, n0 = (j & 7) * 64;
      const float* wa = side ? p.fWrt : p.fWzt;
      const float* wb = side ? p.fWrm : p.fWzm;
      float2 s = job8<JB, 1024, 512, 64>(p, sm, t, nullptr, side, rb, n0, wa, Hd, wb, Hd);
      const int r = e >> 6, c = e & 63, col = n0 + c;
      const int base = (rb + r) * Hd + col;
      const float* bias = side ? p.frb : p.fzb;
      float2 bv = *(const float2*)&bias[col];
      float2 gg = make_float2(sig1(s.x + bv.x), sig1(s.y + bv.y));
      if (side == 0) {
        st2v(ws + OFF_F + base, gg);                 // z
      } else {                                       // r -> R·H
        float2 rt = ld2v(ws + OFF_G + 1 * BbHd + base);
        float2 rm = ld2v(ws + OFF_G + 3 * BbHd + base);
        float2 ho = ld2v(ws + OFF_HB + ((t - 1) & 1) * BbHd + base);
        st2v(ws + OFF_F + BbHd + base,
             make_float2((gg.x * rt.x + (1.f - gg.x) * rm.x) * ho.x,
                         (gg.y * rt.y + (1.f - gg.y) * rm.y) * ho.y));
      }
    } else if (j < 24 && t < Tt) {
      const int jj = j - 16, n0 = jj * 32;
      float2 s = job8<JX, 512, 256, 32>(p, sm, t, nullptr, 0, rb, n0, p.fWxt, Ii, p.fWxm, Ii);
      if (tid < 128) {
        const int r = e >> 5, c = e & 31, col = n0 + c, brow = rb + r;
        float2 bv = *(const float2*)&p.fxb[col];
        float g0 = sig1(s.x + bv.x), g1 = sig1(s.y + bv.y);
        float2 xt = *(const float2*)&p.tt[(brow * Tt + t) * Ii + col];
        float2 xm = *(const float2*)&p.mark[(brow * Tt + t) * Ii + col];
        st2v(ws + OFF_XB + ((t + 1) & 1) * BbIi + brow * Ii + col,
             make_float2(g0 * xt.x + (1.f - g0) * xm.x, g1 * xt.y + (1.f - g1) * xm.y));
      }
    }
    grpbar(ws, g, ++bt);
    // ---------- phase C: H-tilde K=512 + epilogue (16) || Ah(t+1) K=256 (8) ----------
    if (j < 16) {
      const int n0 = j * 32;
      float2 s = job8<JRH, 512, 512, 32>(p, sm, t, nullptr, 0, rb, n0, p.Whh, Hd, p.Whh, Hd);
      if (tid < 128) {
        const int r = e >> 5, c = e & 31, col = n0 + c, brow = rb + r;
        const int base = brow * Hd + col;
        float2 ah = ld2v(ws + OFF_AH + (t & 1) * BbHd + base);
        float2 bv = *(const float2*)&p.bh[col];
        float ht0 = tanh1(s.x + ah.x + bv.x), ht1 = tanh1(s.y + ah.y + bv.y);
        float2 zf = ld2v(ws + OFF_F + base);
        float2 zt = ld2v(ws + OFF_G + base);
        float2 zm = ld2v(ws + OFF_G + 2 * BbHd + base);
        float2 ho = ld2v(ws + OFF_HB + ((t - 1) & 1) * BbHd + base);
        float Z0 = zf.x * zt.x + (1.f - zf.x) * zm.x;
        float Z1 = zf.y * zt.y + (1.f - zf.y) * zm.y;
        float2 hn = make_float2(Z0 * ho.x + (1.f - Z0) * ht0, Z1 * ho.y + (1.f - Z1) * ht1);
        st2v(ws + OFF_HB + (t & 1) * BbHd + base, hn);
        *(float2*)&p.out[(brow * Tt + (t - 1)) * Hd + col] = hn;
        if (t == Tt) *(float2*)&p.out[Bb * Tt * Hd + brow * Hd + col] = hn;
      }
    } else if (j < 24 && t < Tt) {
      const int jj = j - 16, n0 = jj * 64;
      float2 s = job8<JXB, 256, 256, 64>(p, sm, t, nullptr, 0, rb, n0, p.Wxh, Hd, p.Wxh, Hd);
      const int r = e >> 6, c = e & 63, col = n0 + c;
      st2v(ws + OFF_AH + ((t + 1) & 1) * BbHd + (rb + r) * Hd + col, s);
    }
    grpbar(ws, g, ++bt);
  }
}

extern "C" void kernel_launch(void* const* d_in, const int* in_sizes, int n_in,
                              void* d_out, int out_size, void* d_ws, size_t ws_size,
                              hipStream_t stream) {
  P pr;
  pr.tt    = (const float*)d_in[0];
  pr.mark  = (const float*)d_in[1];
  pr.Wxz_t = (const float*)d_in[2];
  pr.Wxr_t = (const float*)d_in[3];
  pr.Wxz_m = (const float*)d_in[4];
  pr.Wxr_m = (const float*)d_in[5];
  pr.Wxh   = (const float*)d_in[6];
  pr.Whz_t = (const float*)d_in[7];
  pr.Whr_t = (const float*)d_in[8];
  pr.Whz_m = (const float*)d_in[9];
  pr.Whr_m = (const float*)d_in[10];
  pr.Whh   = (const float*)d_in[11];
  pr.bz_t  = (const float*)d_in[12];
  pr.br_t  = (const float*)d_in[13];
  pr.bz_m  = (const float*)d_in[14];
  pr.br_m  = (const float*)d_in[15];
  pr.bh    = (const float*)d_in[16];
  pr.fWrt  = (const float*)d_in[17];
  pr.fWrm  = (const float*)d_in[18];
  pr.fWzt  = (const float*)d_in[19];
  pr.fWzm  = (const float*)d_in[20];
  pr.fWxt  = (const float*)d_in[21];
  pr.fWxm  = (const float*)d_in[22];
  pr.frb   = (const float*)d_in[23];
  pr.fzb   = (const float*)d_in[24];
  pr.fxb   = (const float*)d_in[25];
  pr.out = (float*)d_out;
  pr.ws  = (float*)d_ws;

  hipLaunchKernelGGL(ggru_init, dim3(192), dim3(256), 0, stream, (float*)d_ws);

  void* args[] = { (void*)&pr };
  hipError_t err = hipLaunchCooperativeKernel((const void*)ggru_persist,
                                              dim3(NWG), dim3(NTHR),
                                              args, (unsigned)SMEM_BYTES, stream);
  if (err != hipSuccess) {
    hipLaunchKernelGGL(ggru_persist, dim3(NWG), dim3(NTHR), SMEM_BYTES, stream, pr);
  }
}

// Round 10
// 13331.506 us; speedup vs baseline: 3.2469x; 1.3088x over previous
//
#include <hip/hip_runtime.h>

#define DEV __device__ __forceinline__

constexpr int Bb = 64, Tt = 512, Ii = 256, Hd = 512;
constexpr int NWG = 512, NTHR = 256;          // 2 WGs per CU
constexpr int BbHd = Bb * Hd, BbIi = Bb * Ii;

// 8 independent groups × 64 WGs × 8 batch rows. WG wg: g = wg>>6, j = wg&63.
// XCD(wg) = wg%8 = j%8 -> same col-slices land on same XCD for all groups;
// per-XCD weight set = 12.6MB/8 = 1.6MB (L2-resident). wg and wg+256 share j
// -> co-resident WGs on a CU stream identical weight tiles (L1 reuse).

// ---- workspace layout (floats) ----
// [0,16384): sync — per-group: counter @ uint g*64, gen flag @ uint g*64+32
constexpr int OFF_G  = 16384;                 // gates σ'd [4][64][512]
constexpr int OFF_F  = OFF_G + 4 * BbHd;      // F0 = z σ'd; F1 = R·H
constexpr int OFF_HB = OFF_F + 2 * BbHd;      // H double buffer [2][64][512]
constexpr int OFF_XB = OFF_HB + 2 * BbHd;     // X-mixed ring [2][64][256]
constexpr int OFF_AH = OFF_XB + 2 * BbIi;     // Ah preact ring [2][64][512]
// end = 376832 floats = 1.47 MB

#define SMEM_BYTES 32768                      // staging [8][K<=1024]; red aliases

struct P {
  const float *tt, *mark;
  const float *Wxz_t, *Wxr_t, *Wxz_m, *Wxr_m, *Wxh;
  const float *Whz_t, *Whr_t, *Whz_m, *Whr_m, *Whh;
  const float *bz_t, *br_t, *bz_m, *br_m, *bh;
  const float *fWrt, *fWrm, *fWzt, *fWzm, *fWxt, *fWxm;
  const float *frb, *fzb, *fxb;
  float* out; float* ws;
};

enum { JA = 0, JB = 1, JRH = 2, JX = 3, JXB = 4 };

DEV float sig1(float x) { return 1.f / (1.f + __expf(-x)); }
DEV float tanh1(float x) { return 2.f * sig1(2.f * x) - 1.f; }
DEV float4 ld4(const float* p) { return *(const float4*)p; }

// coherent (agent-scope) 8B load/store
DEV float2 ld2v(const float* p) {
  unsigned long long u = __hip_atomic_load((const unsigned long long*)p,
                                           __ATOMIC_RELAXED, __HIP_MEMORY_SCOPE_AGENT);
  return __builtin_bit_cast(float2, u);
}
DEV void st2v(float* p, float2 v) {
  __hip_atomic_store((unsigned long long*)p, __builtin_bit_cast(unsigned long long, v),
                     __ATOMIC_RELAXED, __HIP_MEMORY_SCOPE_AGENT);
}
DEV float4 ld4v(const float* p) {
  float2 a = ld2v(p), b = ld2v(p + 2);
  return make_float4(a.x, a.y, b.x, b.y);
}

// A-operand: 4 consecutive k (groups never straddle segment bounds). b = absolute row.
template<int TYPE>
DEV float4 loadA4(const P& p, int t, const float* aux, int side, int b, int k) {
  const float* ws = p.ws;
  if constexpr (TYPE == JA) {          // [X_raw row t-1 (256) | H(t-1) (512)]
    if (k < Ii) return ld4(&aux[(b * Tt + (t - 1)) * Ii + k]);
    return ld4v(ws + OFF_HB + ((t - 1) & 1) * BbHd + b * Hd + (k - Ii));
  } else if constexpr (TYPE == JB) {   // [Zt|Zm] (side0) / [Rt|Rm] (side1)
    const int g = (k < Hd) ? side : side + 2;
    const int j = (k < Hd) ? k : k - Hd;
    return ld4v(ws + OFF_G + g * BbHd + b * Hd + j);
  } else if constexpr (TYPE == JRH) {  // R·H (512)
    return ld4v(ws + OFF_F + BbHd + b * Hd + k);
  } else if constexpr (TYPE == JX) {   // [Xt_raw | Xm_raw] row t
    if (k < Ii) return ld4(&p.tt[(b * Tt + t) * Ii + k]);
    return ld4(&p.mark[(b * Tt + t) * Ii + (k - Ii)]);
  } else {                             // JXB: X_mixed(t+1) ring (256)
    return ld4v(ws + OFF_XB + ((t + 1) & 1) * BbIi + b * Ii + k);
  }
}

// Full-K GEMM: out tile [8 rows x NC cols] at (rb, n0). A staged once to LDS; weights
// streamed from XCD-local L2; NTHR/(NC/2) k-stripes; LDS reduce. Thread tid owns output
// elems e=2*tid (valid when e < 8*NC): r=e/NC, c=e%NC (local col).
template<int TYPE, int K, int KSPL, int NC>
DEV float2 job8(const P& p, float* lds, int t, const float* aux, int side, int rb,
                int n0, const float* wA, int sA, const float* wB, int sB) {
  const int tid = threadIdx.x;
  constexpr int Kq = K / 4;
  for (int idx = tid; idx < 8 * Kq; idx += NTHR) {
    const int r = idx / Kq, i4 = (idx - r * Kq) * 4;
    float4 v = loadA4<TYPE>(p, t, aux, side, rb + r, i4);
    *(float4*)&lds[r * K + i4] = v;
  }
  __syncthreads();
  constexpr int TPS = NC / 2;          // threads per k-stripe
  constexpr int S = NTHR / TPS;        // k-stripes
  constexpr int Kper = K / S;
  const int kk = tid / TPS, cq = tid % TPS;
  const int c0 = n0 + 2 * cq;
  const int kbase = kk * Kper;
  float acc[8][2] = {};
  #pragma unroll 2
  for (int i = 0; i < Kper / 2; ++i) {
    const int k = kbase + 2 * i;
    const float* wr0 = (k < KSPL) ? &wA[k * sA] : &wB[(k - KSPL) * sB];
    const float* wr1 = (k + 1 < KSPL) ? &wA[(k + 1) * sA] : &wB[(k + 1 - KSPL) * sB];
    float2 w0 = *(const float2*)&wr0[c0];
    float2 w1 = *(const float2*)&wr1[c0];
    #pragma unroll
    for (int r = 0; r < 8; ++r) {
      float2 a = *(const float2*)&lds[r * K + k];
      acc[r][0] = fmaf(a.y, w1.x, fmaf(a.x, w0.x, acc[r][0]));
      acc[r][1] = fmaf(a.y, w1.y, fmaf(a.x, w0.y, acc[r][1]));
    }
  }
  __syncthreads();
  float* red = lds;                    // [S][8*NC], aliases staging
  #pragma unroll
  for (int r = 0; r < 8; ++r)
    *(float2*)&red[(kk * 8 + r) * NC + 2 * cq] = make_float2(acc[r][0], acc[r][1]);
  __syncthreads();
  float2 s = make_float2(0.f, 0.f);
  const int e = tid * 2;
  if (e < 8 * NC) {
    #pragma unroll
    for (int q = 0; q < S; ++q) {
      float2 v = *(const float2*)&red[q * 8 * NC + e];
      s.x += v.x; s.y += v.y;
    }
  }
  return s;
}

// group barrier: 64 WGs, monotonic target
DEV void grpbar(float* ws, int g, unsigned tgt) {
  __syncthreads();
  if (threadIdx.x == 0) {
    asm volatile("s_waitcnt vmcnt(0)" ::: "memory");
    unsigned* cnt = (unsigned*)ws + g * 64;
    unsigned* gen = (unsigned*)ws + g * 64 + 32;
    unsigned a = __hip_atomic_fetch_add(cnt, 1u, __ATOMIC_RELAXED, __HIP_MEMORY_SCOPE_AGENT);
    if (a == 64u * tgt - 1u)
      __hip_atomic_store(gen, tgt, __ATOMIC_RELAXED, __HIP_MEMORY_SCOPE_AGENT);
    while (__hip_atomic_load(gen, __ATOMIC_RELAXED, __HIP_MEMORY_SCOPE_AGENT) < tgt)
      __builtin_amdgcn_s_sleep(1);
  }
  __syncthreads();
}

__global__ void ggru_init(float* ws) {
  const int i = blockIdx.x * 256 + threadIdx.x;
  if (i < 16384) ws[i] = 0.f;                       // sync region
  const int j = i - 16384;
  if (j >= 0 && j < BbHd) ws[OFF_HB + j] = 0.f;     // H0 = 0 (buffer 0)
}

__global__ __launch_bounds__(NTHR)
void ggru_persist(P p) {
  extern __shared__ float sm[];
  const int wg = blockIdx.x, tid = threadIdx.x;
  const int g = wg >> 6, j = wg & 63, rb = g * 8;   // group, slot, batch-row base
  float* ws = p.ws;
  unsigned bt = 0;
  const int e = tid * 2;

  // ---------- prologue: X-mix(1) then Ah(1) ----------
  if (j < 16) {
    float2 s = job8<JX, 512, 256, 16>(p, sm, 0, nullptr, 0, rb, j * 16, p.fWxt, Ii, p.fWxm, Ii);
    if (tid < 64) {
      const int r = e >> 4, c = e & 15, col = j * 16 + c, brow = rb + r;
      float2 bv = *(const float2*)&p.fxb[col];
      float g0 = sig1(s.x + bv.x), g1 = sig1(s.y + bv.y);
      float2 xt = *(const float2*)&p.tt[(brow * Tt + 0) * Ii + col];
      float2 xm = *(const float2*)&p.mark[(brow * Tt + 0) * Ii + col];
      st2v(ws + OFF_XB + 1 * BbIi + brow * Ii + col,
           make_float2(g0 * xt.x + (1.f - g0) * xm.x, g1 * xt.y + (1.f - g1) * xm.y));
    }
  }
  grpbar(ws, g, ++bt);
  if (j < 16) {
    float2 s = job8<JXB, 256, 256, 32>(p, sm, 0, nullptr, 0, rb, j * 32, p.Wxh, Hd, p.Wxh, Hd);
    if (tid < 128) {
      const int r = e >> 5, c = e & 31, col = j * 32 + c;
      st2v(ws + OFF_AH + 1 * BbHd + (rb + r) * Hd + col, s);
    }
  }
  grpbar(ws, g, ++bt);

  for (int t = 1; t <= Tt; ++t) {
    // ---------- phase A: 4 gates, K=768; all 64 slots (NC=32) ----------
    {
      const int gate = j >> 4, cb = j & 15, n0 = cb * 32;
      const float* wx = gate==0 ? p.Wxz_t : gate==1 ? p.Wxr_t : gate==2 ? p.Wxz_m : p.Wxr_m;
      const float* wh = gate==0 ? p.Whz_t : gate==1 ? p.Whr_t : gate==2 ? p.Whz_m : p.Whr_m;
      const float* xin = (gate < 2) ? p.tt : p.mark;
      float2 s = job8<JA, 768, 256, 32>(p, sm, t, xin, 0, rb, n0, wx, Hd, wh, Hd);
      if (tid < 128) {
        const int r = e >> 5, c = e & 31, col = n0 + c;
        const float* bias = gate==0 ? p.bz_t : gate==1 ? p.br_t : gate==2 ? p.bz_m : p.br_m;
        float2 bv = *(const float2*)&bias[col];
        st2v(ws + OFF_G + gate * BbHd + (rb + r) * Hd + col,
             make_float2(sig1(s.x + bv.x), sig1(s.y + bv.y)));
      }
    }
    grpbar(ws, g, ++bt);
    // ---------- phase B: z/r K=1024 (32 slots, NC=32) || X-mix(t+1) (16 slots, NC=16) ----------
    if (j < 32) {
      const int side = j >> 4, n0 = (j & 15) * 32;
      const float* wa = side ? p.fWrt : p.fWzt;
      const float* wb = side ? p.fWrm : p.fWzm;
      float2 s = job8<JB, 1024, 512, 32>(p, sm, t, nullptr, side, rb, n0, wa, Hd, wb, Hd);
      if (tid < 128) {
        const int r = e >> 5, c = e & 31, col = n0 + c;
        const int base = (rb + r) * Hd + col;
        const float* bias = side ? p.frb : p.fzb;
        float2 bv = *(const float2*)&bias[col];
        float2 gg = make_float2(sig1(s.x + bv.x), sig1(s.y + bv.y));
        if (side == 0) {
          st2v(ws + OFF_F + base, gg);               // z
        } else {                                     // r -> R·H
          float2 rt = ld2v(ws + OFF_G + 1 * BbHd + base);
          float2 rm = ld2v(ws + OFF_G + 3 * BbHd + base);
          float2 ho = ld2v(ws + OFF_HB + ((t - 1) & 1) * BbHd + base);
          st2v(ws + OFF_F + BbHd + base,
               make_float2((gg.x * rt.x + (1.f - gg.x) * rm.x) * ho.x,
                           (gg.y * rt.y + (1.f - gg.y) * rm.y) * ho.y));
        }
      }
    } else if (j < 48 && t < Tt) {
      const int jj = j - 32, n0 = jj * 16;
      float2 s = job8<JX, 512, 256, 16>(p, sm, t, nullptr, 0, rb, n0, p.fWxt, Ii, p.fWxm, Ii);
      if (tid < 64) {
        const int r = e >> 4, c = e & 15, col = n0 + c, brow = rb + r;
        float2 bv = *(const float2*)&p.fxb[col];
        float g0 = sig1(s.x + bv.x), g1 = sig1(s.y + bv.y);
        float2 xt = *(const float2*)&p.tt[(brow * Tt + t) * Ii + col];
        float2 xm = *(const float2*)&p.mark[(brow * Tt + t) * Ii + col];
        st2v(ws + OFF_XB + ((t + 1) & 1) * BbIi + brow * Ii + col,
             make_float2(g0 * xt.x + (1.f - g0) * xm.x, g1 * xt.y + (1.f - g1) * xm.y));
      }
    }
    grpbar(ws, g, ++bt);
    // ---------- phase C: H-tilde K=512 (32 slots, NC=16) || Ah(t+1) K=256 (16, NC=32) ----------
    if (j < 32) {
      const int n0 = j * 16;
      float2 s = job8<JRH, 512, 512, 16>(p, sm, t, nullptr, 0, rb, n0, p.Whh, Hd, p.Whh, Hd);
      if (tid < 64) {
        const int r = e >> 4, c = e & 15, col = n0 + c, brow = rb + r;
        const int base = brow * Hd + col;
        float2 ah = ld2v(ws + OFF_AH + (t & 1) * BbHd + base);
        float2 bv = *(const float2*)&p.bh[col];
        float ht0 = tanh1(s.x + ah.x + bv.x), ht1 = tanh1(s.y + ah.y + bv.y);
        float2 zf = ld2v(ws + OFF_F + base);
        float2 zt = ld2v(ws + OFF_G + base);
        float2 zm = ld2v(ws + OFF_G + 2 * BbHd + base);
        float2 ho = ld2v(ws + OFF_HB + ((t - 1) & 1) * BbHd + base);
        float Z0 = zf.x * zt.x + (1.f - zf.x) * zm.x;
        float Z1 = zf.y * zt.y + (1.f - zf.y) * zm.y;
        float2 hn = make_float2(Z0 * ho.x + (1.f - Z0) * ht0, Z1 * ho.y + (1.f - Z1) * ht1);
        st2v(ws + OFF_HB + (t & 1) * BbHd + base, hn);
        *(float2*)&p.out[(brow * Tt + (t - 1)) * Hd + col] = hn;
        if (t == Tt) *(float2*)&p.out[Bb * Tt * Hd + brow * Hd + col] = hn;
      }
    } else if (j < 48 && t < Tt) {
      const int jj = j - 32, n0 = jj * 32;
      float2 s = job8<JXB, 256, 256, 32>(p, sm, t, nullptr, 0, rb, n0, p.Wxh, Hd, p.Wxh, Hd);
      if (tid < 128) {
        const int r = e >> 5, c = e & 31, col = n0 + c;
        st2v(ws + OFF_AH + ((t + 1) & 1) * BbHd + (rb + r) * Hd + col, s);
      }
    }
    grpbar(ws, g, ++bt);
  }
}

extern "C" void kernel_launch(void* const* d_in, const int* in_sizes, int n_in,
                              void* d_out, int out_size, void* d_ws, size_t ws_size,
                              hipStream_t stream) {
  P pr;
  pr.tt    = (const float*)d_in[0];
  pr.mark  = (const float*)d_in[1];
  pr.Wxz_t = (const float*)d_in[2];
  pr.Wxr_t = (const float*)d_in[3];
  pr.Wxz_m = (const float*)d_in[4];
  pr.Wxr_m = (const float*)d_in[5];
  pr.Wxh   = (const float*)d_in[6];
  pr.Whz_t = (const float*)d_in[7];
  pr.Whr_t = (const float*)d_in[8];
  pr.Whz_m = (const float*)d_in[9];
  pr.Whr_m = (const float*)d_in[10];
  pr.Whh   = (const float*)d_in[11];
  pr.bz_t  = (const float*)d_in[12];
  pr.br_t  = (const float*)d_in[13];
  pr.bz_m  = (const float*)d_in[14];
  pr.br_m  = (const float*)d_in[15];
  pr.bh    = (const float*)d_in[16];
  pr.fWrt  = (const float*)d_in[17];
  pr.fWrm  = (const float*)d_in[18];
  pr.fWzt  = (const float*)d_in[19];
  pr.fWzm  = (const float*)d_in[20];
  pr.fWxt  = (const float*)d_in[21];
  pr.fWxm  = (const float*)d_in[22];
  pr.frb   = (const float*)d_in[23];
  pr.fzb   = (const float*)d_in[24];
  pr.fxb   = (const float*)d_in[25];
  pr.out = (float*)d_out;
  pr.ws  = (float*)d_ws;

  hipLaunchKernelGGL(ggru_init, dim3(192), dim3(256), 0, stream, (float*)d_ws);

  void* args[] = { (void*)&pr };
  hipError_t err = hipLaunchCooperativeKernel((const void*)ggru_persist,
                                              dim3(NWG), dim3(NTHR),
                                              args, (unsigned)SMEM_BYTES, stream);
  if (err != hipSuccess) {
    hipLaunchKernelGGL(ggru_persist, dim3(NWG), dim3(NTHR), SMEM_BYTES, stream, pr);
  }
}

// Round 11
// 11603.102 us; speedup vs baseline: 3.7306x; 1.1490x over previous
//
#include <hip/hip_runtime.h>

#define DEV __device__ __forceinline__

constexpr int Bb = 64, Tt = 512, Ii = 256, Hd = 512;
constexpr int NWG = 512, NTHR = 256;          // 2 WGs per CU
constexpr int BbHd = Bb * Hd, BbIi = Bb * Ii;

// 8 independent groups × 64 WGs × 8 batch rows. WG wg: g = wg>>6, j = wg&63.
// XCD(wg) = wg%8 = j%8 -> same col-slices land on same XCD for all groups;
// per-XCD weight set = 12.6MB/8 = 1.6MB (L2-resident). wg and wg+256 share j
// -> co-resident WGs on a CU stream identical weight tiles (L1 reuse).

// ---- workspace layout (floats) ----
// [0,16384): sync — per-group: counter @ uint g*64, gen flag @ uint g*64+32
constexpr int OFF_G  = 16384;                 // gates σ'd [4][64][512]
constexpr int OFF_F  = OFF_G + 4 * BbHd;      // F0 = z σ'd; F1 = R·H
constexpr int OFF_HB = OFF_F + 2 * BbHd;      // H double buffer [2][64][512]
constexpr int OFF_XB = OFF_HB + 2 * BbHd;     // X-mixed ring [2][64][256]
constexpr int OFF_AH = OFF_XB + 2 * BbIi;     // Ah preact ring [2][64][512]
// end = 376832 floats = 1.47 MB

#define SMEM_BYTES 32768                      // staging [8][K<=1024]; red aliases

struct P {
  const float *tt, *mark;
  const float *Wxz_t, *Wxr_t, *Wxz_m, *Wxr_m, *Wxh;
  const float *Whz_t, *Whr_t, *Whz_m, *Whr_m, *Whh;
  const float *bz_t, *br_t, *bz_m, *br_m, *bh;
  const float *fWrt, *fWrm, *fWzt, *fWzm, *fWxt, *fWxm;
  const float *frb, *fzb, *fxb;
  float* out; float* ws;
};

enum { JA = 0, JB = 1, JRH = 2, JX = 3, JXB = 4 };

DEV float sig1(float x) { return 1.f / (1.f + __expf(-x)); }
DEV float tanh1(float x) { return 2.f * sig1(2.f * x) - 1.f; }
DEV float4 ld4(const float* p) { return *(const float4*)p; }

// coherent (agent-scope) 8B load/store
DEV float2 ld2v(const float* p) {
  unsigned long long u = __hip_atomic_load((const unsigned long long*)p,
                                           __ATOMIC_RELAXED, __HIP_MEMORY_SCOPE_AGENT);
  return __builtin_bit_cast(float2, u);
}
DEV void st2v(float* p, float2 v) {
  __hip_atomic_store((unsigned long long*)p, __builtin_bit_cast(unsigned long long, v),
                     __ATOMIC_RELAXED, __HIP_MEMORY_SCOPE_AGENT);
}
DEV float4 ld4v(const float* p) {
  float2 a = ld2v(p), b = ld2v(p + 2);
  return make_float4(a.x, a.y, b.x, b.y);
}

// A-operand: 4 consecutive k (groups never straddle segment bounds). b = absolute row.
template<int TYPE>
DEV float4 loadA4(const P& p, int t, const float* aux, int side, int b, int k) {
  const float* ws = p.ws;
  if constexpr (TYPE == JA) {          // [X_raw row t-1 (256) | H(t-1) (512)]
    if (k < Ii) return ld4(&aux[(b * Tt + (t - 1)) * Ii + k]);
    return ld4v(ws + OFF_HB + ((t - 1) & 1) * BbHd + b * Hd + (k - Ii));
  } else if constexpr (TYPE == JB) {   // [Zt|Zm] (side0) / [Rt|Rm] (side1)
    const int g = (k < Hd) ? side : side + 2;
    const int j = (k < Hd) ? k : k - Hd;
    return ld4v(ws + OFF_G + g * BbHd + b * Hd + j);
  } else if constexpr (TYPE == JRH) {  // R·H (512)
    return ld4v(ws + OFF_F + BbHd + b * Hd + k);
  } else if constexpr (TYPE == JX) {   // [Xt_raw | Xm_raw] row t
    if (k < Ii) return ld4(&p.tt[(b * Tt + t) * Ii + k]);
    return ld4(&p.mark[(b * Tt + t) * Ii + (k - Ii)]);
  } else {                             // JXB: X_mixed(t+1) ring (256)
    return ld4v(ws + OFF_XB + ((t + 1) & 1) * BbIi + b * Ii + k);
  }
}

// Full-K GEMM: out tile [8 rows x NC cols] at (rb, n0). A staged once to LDS; weights
// streamed from XCD-local L2; CPT cols per thread; S = NTHR/(NC/CPT) k-stripes;
// LDS reduce. Thread tid owns output elems e=2*tid (valid when e < 8*NC).
template<int TYPE, int K, int KSPL, int NC, int CPT>
DEV float2 job8(const P& p, float* lds, int t, const float* aux, int side, int rb,
                int n0, const float* wA, int sA, const float* wB, int sB) {
  const int tid = threadIdx.x;
  constexpr int Kq = K / 4;
  for (int idx = tid; idx < 8 * Kq; idx += NTHR) {
    const int r = idx / Kq, i4 = (idx - r * Kq) * 4;
    float4 v = loadA4<TYPE>(p, t, aux, side, rb + r, i4);
    *(float4*)&lds[r * K + i4] = v;
  }
  __syncthreads();
  constexpr int TPS = NC / CPT;        // threads per k-stripe
  constexpr int S = NTHR / TPS;        // k-stripes
  constexpr int Kper = K / S;
  const int kk = tid / TPS, cq = tid % TPS;
  const int c0 = n0 + CPT * cq;
  const int kbase = kk * Kper;
  float acc[8][CPT] = {};
  #pragma unroll 2
  for (int i = 0; i < Kper / 2; ++i) {
    const int k = kbase + 2 * i;
    const float* wr0 = (k < KSPL) ? &wA[k * sA] : &wB[(k - KSPL) * sB];
    const float* wr1 = (k + 1 < KSPL) ? &wA[(k + 1) * sA] : &wB[(k + 1 - KSPL) * sB];
    float w0[CPT], w1[CPT];
    if constexpr (CPT == 4) {
      float4 u0 = ld4(&wr0[c0]); w0[0]=u0.x; w0[1]=u0.y; w0[2]=u0.z; w0[3]=u0.w;
      float4 u1 = ld4(&wr1[c0]); w1[0]=u1.x; w1[1]=u1.y; w1[2]=u1.z; w1[3]=u1.w;
    } else {
      float2 u0 = *(const float2*)&wr0[c0]; w0[0]=u0.x; w0[1]=u0.y;
      float2 u1 = *(const float2*)&wr1[c0]; w1[0]=u1.x; w1[1]=u1.y;
    }
    #pragma unroll
    for (int r = 0; r < 8; ++r) {
      float2 a = *(const float2*)&lds[r * K + k];
      #pragma unroll
      for (int c = 0; c < CPT; ++c)
        acc[r][c] = fmaf(a.y, w1[c], fmaf(a.x, w0[c], acc[r][c]));
    }
  }
  __syncthreads();
  float* red = lds;                    // [S][8*NC], aliases staging (<= 32KB)
  #pragma unroll
  for (int r = 0; r < 8; ++r) {
    if constexpr (CPT == 4) {
      *(float4*)&red[(kk * 8 + r) * NC + CPT * cq] =
          make_float4(acc[r][0], acc[r][1], acc[r][2], acc[r][3]);
    } else {
      *(float2*)&red[(kk * 8 + r) * NC + CPT * cq] = make_float2(acc[r][0], acc[r][1]);
    }
  }
  __syncthreads();
  float2 s = make_float2(0.f, 0.f);
  const int e = tid * 2;
  if (e < 8 * NC) {
    #pragma unroll
    for (int q = 0; q < S; ++q) {
      float2 v = *(const float2*)&red[q * 8 * NC + e];
      s.x += v.x; s.y += v.y;
    }
  }
  return s;
}

// group barrier: 64 WGs, monotonic target
DEV void grpbar(float* ws, int g, unsigned tgt) {
  __syncthreads();
  if (threadIdx.x == 0) {
    asm volatile("s_waitcnt vmcnt(0)" ::: "memory");
    unsigned* cnt = (unsigned*)ws + g * 64;
    unsigned* gen = (unsigned*)ws + g * 64 + 32;
    unsigned a = __hip_atomic_fetch_add(cnt, 1u, __ATOMIC_RELAXED, __HIP_MEMORY_SCOPE_AGENT);
    if (a == 64u * tgt - 1u)
      __hip_atomic_store(gen, tgt, __ATOMIC_RELAXED, __HIP_MEMORY_SCOPE_AGENT);
    while (__hip_atomic_load(gen, __ATOMIC_RELAXED, __HIP_MEMORY_SCOPE_AGENT) < tgt)
      __builtin_amdgcn_s_sleep(1);
  }
  __syncthreads();
}

__global__ void ggru_init(float* ws) {
  const int i = blockIdx.x * 256 + threadIdx.x;
  if (i < 16384) ws[i] = 0.f;                       // sync region
  const int j = i - 16384;
  if (j >= 0 && j < BbHd) ws[OFF_HB + j] = 0.f;     // H0 = 0 (buffer 0)
}

__global__ __launch_bounds__(NTHR)
void ggru_persist(P p) {
  extern __shared__ float sm[];
  const int wg = blockIdx.x, tid = threadIdx.x;
  const int g = wg >> 6, j = wg & 63, rb = g * 8;   // group, slot, batch-row base
  float* ws = p.ws;
  unsigned bt = 0;
  const int e = tid * 2;

  // ---------- prologue: X-mix(1) then Ah(1) ----------
  if (j < 16) {
    float2 s = job8<JX, 512, 256, 16, 2>(p, sm, 0, nullptr, 0, rb, j * 16, p.fWxt, Ii, p.fWxm, Ii);
    if (tid < 64) {
      const int r = e >> 4, c = e & 15, col = j * 16 + c, brow = rb + r;
      float2 bv = *(const float2*)&p.fxb[col];
      float g0 = sig1(s.x + bv.x), g1 = sig1(s.y + bv.y);
      float2 xt = *(const float2*)&p.tt[(brow * Tt + 0) * Ii + col];
      float2 xm = *(const float2*)&p.mark[(brow * Tt + 0) * Ii + col];
      st2v(ws + OFF_XB + 1 * BbIi + brow * Ii + col,
           make_float2(g0 * xt.x + (1.f - g0) * xm.x, g1 * xt.y + (1.f - g1) * xm.y));
    }
  }
  grpbar(ws, g, ++bt);
  if (j < 16) {
    float2 s = job8<JXB, 256, 256, 32, 4>(p, sm, 0, nullptr, 0, rb, j * 32, p.Wxh, Hd, p.Wxh, Hd);
    if (tid < 128) {
      const int r = e >> 5, c = e & 31, col = j * 32 + c;
      st2v(ws + OFF_AH + 1 * BbHd + (rb + r) * Hd + col, s);
    }
  }
  grpbar(ws, g, ++bt);

  for (int t = 1; t <= Tt; ++t) {
    // ---------- phase A: 4 gates, K=768; all 64 slots (NC=32) ----------
    {
      const int gate = j >> 4, cb = j & 15, n0 = cb * 32;
      const float* wx = gate==0 ? p.Wxz_t : gate==1 ? p.Wxr_t : gate==2 ? p.Wxz_m : p.Wxr_m;
      const float* wh = gate==0 ? p.Whz_t : gate==1 ? p.Whr_t : gate==2 ? p.Whz_m : p.Whr_m;
      const float* xin = (gate < 2) ? p.tt : p.mark;
      float2 s = job8<JA, 768, 256, 32, 4>(p, sm, t, xin, 0, rb, n0, wx, Hd, wh, Hd);
      if (tid < 128) {
        const int r = e >> 5, c = e & 31, col = n0 + c;
        const float* bias = gate==0 ? p.bz_t : gate==1 ? p.br_t : gate==2 ? p.bz_m : p.br_m;
        float2 bv = *(const float2*)&bias[col];
        st2v(ws + OFF_G + gate * BbHd + (rb + r) * Hd + col,
             make_float2(sig1(s.x + bv.x), sig1(s.y + bv.y)));
      }
    }
    grpbar(ws, g, ++bt);
    // ---------- phase B: z/r K=1024 (32 slots, NC=32) || X-mix(t+1) (16 slots, NC=16) ----------
    if (j < 32) {
      const int side = j >> 4, n0 = (j & 15) * 32;
      const float* wa = side ? p.fWrt : p.fWzt;
      const float* wb = side ? p.fWrm : p.fWzm;
      float2 s = job8<JB, 1024, 512, 32, 4>(p, sm, t, nullptr, side, rb, n0, wa, Hd, wb, Hd);
      if (tid < 128) {
        const int r = e >> 5, c = e & 31, col = n0 + c;
        const int base = (rb + r) * Hd + col;
        const float* bias = side ? p.frb : p.fzb;
        float2 bv = *(const float2*)&bias[col];
        float2 gg = make_float2(sig1(s.x + bv.x), sig1(s.y + bv.y));
        if (side == 0) {
          st2v(ws + OFF_F + base, gg);               // z
        } else {                                     // r -> R·H
          float2 rt = ld2v(ws + OFF_G + 1 * BbHd + base);
          float2 rm = ld2v(ws + OFF_G + 3 * BbHd + base);
          float2 ho = ld2v(ws + OFF_HB + ((t - 1) & 1) * BbHd + base);
          st2v(ws + OFF_F + BbHd + base,
               make_float2((gg.x * rt.x + (1.f - gg.x) * rm.x) * ho.x,
                           (gg.y * rt.y + (1.f - gg.y) * rm.y) * ho.y));
        }
      }
    } else if (j < 48 && t < Tt) {
      const int jj = j - 32, n0 = jj * 16;
      float2 s = job8<JX, 512, 256, 16, 2>(p, sm, t, nullptr, 0, rb, n0, p.fWxt, Ii, p.fWxm, Ii);
      if (tid < 64) {
        const int r = e >> 4, c = e & 15, col = n0 + c, brow = rb + r;
        float2 bv = *(const float2*)&p.fxb[col];
        float g0 = sig1(s.x + bv.x), g1 = sig1(s.y + bv.y);
        float2 xt = *(const float2*)&p.tt[(brow * Tt + t) * Ii + col];
        float2 xm = *(const float2*)&p.mark[(brow * Tt + t) * Ii + col];
        st2v(ws + OFF_XB + ((t + 1) & 1) * BbIi + brow * Ii + col,
             make_float2(g0 * xt.x + (1.f - g0) * xm.x, g1 * xt.y + (1.f - g1) * xm.y));
      }
    }
    grpbar(ws, g, ++bt);
    // ---------- phase C: H-tilde K=512 (32 slots, NC=16) || Ah(t+1) K=256 (16, NC=32) ----------
    if (j < 32) {
      const int n0 = j * 16;
      float2 s = job8<JRH, 512, 512, 16, 2>(p, sm, t, nullptr, 0, rb, n0, p.Whh, Hd, p.Whh, Hd);
      if (tid < 64) {
        const int r = e >> 4, c = e & 15, col = n0 + c, brow = rb + r;
        const int base = brow * Hd + col;
        float2 ah = ld2v(ws + OFF_AH + (t & 1) * BbHd + base);
        float2 bv = *(const float2*)&p.bh[col];
        float ht0 = tanh1(s.x + ah.x + bv.x), ht1 = tanh1(s.y + ah.y + bv.y);
        float2 zf = ld2v(ws + OFF_F + base);
        float2 zt = ld2v(ws + OFF_G + base);
        float2 zm = ld2v(ws + OFF_G + 2 * BbHd + base);
        float2 ho = ld2v(ws + OFF_HB + ((t - 1) & 1) * BbHd + base);
        float Z0 = zf.x * zt.x + (1.f - zf.x) * zm.x;
        float Z1 = zf.y * zt.y + (1.f - zf.y) * zm.y;
        float2 hn = make_float2(Z0 * ho.x + (1.f - Z0) * ht0, Z1 * ho.y + (1.f - Z1) * ht1);
        st2v(ws + OFF_HB + (t & 1) * BbHd + base, hn);
        *(float2*)&p.out[(brow * Tt + (t - 1)) * Hd + col] = hn;
        if (t == Tt) *(float2*)&p.out[Bb * Tt * Hd + brow * Hd + col] = hn;
      }
    } else if (j < 48 && t < Tt) {
      const int jj = j - 32, n0 = jj * 32;
      float2 s = job8<JXB, 256, 256, 32, 4>(p, sm, t, nullptr, 0, rb, n0, p.Wxh, Hd, p.Wxh, Hd);
      if (tid < 128) {
        const int r = e >> 5, c = e & 31, col = n0 + c;
        st2v(ws + OFF_AH + ((t + 1) & 1) * BbHd + (rb + r) * Hd + col, s);
      }
    }
    grpbar(ws, g, ++bt);
  }
}

extern "C" void kernel_launch(void* const* d_in, const int* in_sizes, int n_in,
                              void* d_out, int out_size, void* d_ws, size_t ws_size,
                              hipStream_t stream) {
  P pr;
  pr.tt    = (const float*)d_in[0];
  pr.mark  = (const float*)d_in[1];
  pr.Wxz_t = (const float*)d_in[2];
  pr.Wxr_t = (const float*)d_in[3];
  pr.Wxz_m = (const float*)d_in[4];
  pr.Wxr_m = (const float*)d_in[5];
  pr.Wxh   = (const float*)d_in[6];
  pr.Whz_t = (const float*)d_in[7];
  pr.Whr_t = (const float*)d_in[8];
  pr.Whz_m = (const float*)d_in[9];
  pr.Whr_m = (const float*)d_in[10];
  pr.Whh   = (const float*)d_in[11];
  pr.bz_t  = (const float*)d_in[12];
  pr.br_t  = (const float*)d_in[13];
  pr.bz_m  = (const float*)d_in[14];
  pr.br_m  = (const float*)d_in[15];
  pr.bh    = (const float*)d_in[16];
  pr.fWrt  = (const float*)d_in[17];
  pr.fWrm  = (const float*)d_in[18];
  pr.fWzt  = (const float*)d_in[19];
  pr.fWzm  = (const float*)d_in[20];
  pr.fWxt  = (const float*)d_in[21];
  pr.fWxm  = (const float*)d_in[22];
  pr.frb   = (const float*)d_in[23];
  pr.fzb   = (const float*)d_in[24];
  pr.fxb   = (const float*)d_in[25];
  pr.out = (float*)d_out;
  pr.ws  = (float*)d_ws;

  hipLaunchKernelGGL(ggru_init, dim3(192), dim3(256), 0, stream, (float*)d_ws);

  void* args[] = { (void*)&pr };
  hipError_t err = hipLaunchCooperativeKernel((const void*)ggru_persist,
                                              dim3(NWG), dim3(NTHR),
                                              args, (unsigned)SMEM_BYTES, stream);
  if (err != hipSuccess) {
    hipLaunchKernelGGL(ggru_persist, dim3(NWG), dim3(NTHR), SMEM_BYTES, stream, pr);
  }
}